// Round 4
// baseline (618.358 us; speedup 1.0000x reference)
//
#include <hip/hip_runtime.h>

// EquivLayerNorm: irreps = 128x0e + 64x1o + 32x2e, DIM=480, fp32.
// Per row: mean over the 128 scalars (only segment that gets centered,
// CENTERIZE_VECTORS=False); unbiased norm^2 per irrep (denoms 127/63/31);
// out = scale[ir] * centered/sqrt(v+eps) + (ir==0 ? offset0 : 0).
//
// One wave (64 lanes) per row. Lane i: float4 @ elem 4*i  (covers [0,256)),
// float4 @ elem 256+4*i for lanes<56 (covers [256,480)). Segment boundaries
// 128/320/480 are all float4-aligned. Row stride 1920 B -> 16B aligned.
// Variance via sum(x^2) - n*mean^2 so a single read pass suffices.
// Grid capped at 2048 blocks, grid-stride over rows (G11, memory-bound).

#define DIM 480

__global__ __launch_bounds__(256) void
eln_kernel(const float* __restrict__ feat,
           const float* __restrict__ scale,
           const float* __restrict__ offset0,
           float* __restrict__ out,
           int nrows)
{
    const int wave = threadIdx.x >> 6;          // 0..3, one row per wave
    const int lane = threadIdx.x & 63;

    // uniform parameters — hoisted out of the row loop (L1/L2-resident)
    const float sc0 = scale[0], sc1 = scale[1], sc2 = scale[2];
    const float off0 = offset0[0];
    const float eps = 1e-8f;

    const long rows_per_pass = (long)gridDim.x * 4;

    for (long row = (long)blockIdx.x * 4 + wave; row < nrows; row += rows_per_pass) {
        const float4* __restrict__ fin =
            reinterpret_cast<const float4*>(feat + row * (long)DIM);
        float4* __restrict__ fout =
            reinterpret_cast<float4*>(out + row * (long)DIM);

        // ---- load (coalesced, 16 B/lane) ----
        float4 a = fin[lane];                    // elems [4*lane, 4*lane+4) in [0,256)
        float4 b = make_float4(0.f, 0.f, 0.f, 0.f);
        const bool b_ok = (lane < 56);           // elems [256,480)
        if (b_ok) b = fin[64 + lane];

        // ---- per-lane partial sums ----
        // a: lanes 0-31 -> seg0 (scalars), lanes 32-63 -> seg1 (1o, first half)
        // b: lanes 0-15 -> seg1 (1o, rest), lanes 16-55 -> seg2 (2e)
        float s0 = 0.f, q0 = 0.f, q1 = 0.f, q2 = 0.f;
        const float qa = a.x*a.x + a.y*a.y + a.z*a.z + a.w*a.w;
        if (lane < 32) {
            s0 = a.x + a.y + a.z + a.w;
            q0 = qa;
        } else {
            q1 = qa;
        }
        if (b_ok) {
            const float qb = b.x*b.x + b.y*b.y + b.z*b.z + b.w*b.w;
            if (lane < 16) q1 += qb; else q2 += qb;
        }

        // ---- wave (64-lane) butterfly reductions ----
        #pragma unroll
        for (int off = 32; off > 0; off >>= 1) {
            s0 += __shfl_xor(s0, off, 64);
            q0 += __shfl_xor(q0, off, 64);
            q1 += __shfl_xor(q1, off, 64);
            q2 += __shfl_xor(q2, off, 64);
        }

        // ---- per-row stats ----
        const float mean = s0 * (1.0f / 128.0f);
        const float v0 = (q0 - 128.0f * mean * mean) * (1.0f / 127.0f);
        const float v1 = q1 * (1.0f / 63.0f);
        const float v2 = q2 * (1.0f / 31.0f);
        // precise 1/sqrt (3 per row -> cost nil; matches jnp sqrt+div closely)
        const float r0 = sc0 / sqrtf(v0 + eps);
        const float r1 = sc1 / sqrtf(v1 + eps);
        const float r2 = sc2 / sqrtf(v2 + eps);

        // ---- normalize + write (coalesced) ----
        float4 oa;
        if (lane < 32) {
            oa.x = (a.x - mean) * r0 + off0;
            oa.y = (a.y - mean) * r0 + off0;
            oa.z = (a.z - mean) * r0 + off0;
            oa.w = (a.w - mean) * r0 + off0;
        } else {
            oa.x = a.x * r1;
            oa.y = a.y * r1;
            oa.z = a.z * r1;
            oa.w = a.w * r1;
        }
        fout[lane] = oa;

        if (b_ok) {
            const float rr = (lane < 16) ? r1 : r2;
            float4 ob;
            ob.x = b.x * rr;
            ob.y = b.y * rr;
            ob.z = b.z * rr;
            ob.w = b.w * rr;
            fout[64 + lane] = ob;
        }
    }
}

extern "C" void kernel_launch(void* const* d_in, const int* in_sizes, int n_in,
                              void* d_out, int out_size, void* d_ws, size_t ws_size,
                              hipStream_t stream)
{
    const float* feat    = (const float*)d_in[0];
    const float* scale   = (const float*)d_in[1];
    const float* offset0 = (const float*)d_in[2];
    float* out = (float*)d_out;

    const int nrows = in_sizes[0] / DIM;          // 200000
    int blocks = (nrows + 3) / 4;                 // 4 rows (waves) per 256-thr block
    if (blocks > 2048) blocks = 2048;             // G11: cap + grid-stride
    eln_kernel<<<blocks, 256, 0, stream>>>(feat, scale, offset0, out, nrows);
}

// Round 7
// 582.881 us; speedup vs baseline: 1.0609x; 1.0609x over previous
//
#include <hip/hip_runtime.h>

// EquivLayerNorm: irreps = 128x0e + 64x1o + 32x2e, DIM=480, fp32.
// Per row: mean over the 128 scalars (only segment that gets centered,
// CENTERIZE_VECTORS=False); unbiased norm^2 per irrep (denoms 127/63/31);
// out = scale[ir] * centered/sqrt(v+eps) + (ir==0 ? offset0 : 0).
//
// One wave (64 lanes) per row, one-shot grid (50000 blocks x 4 waves).
// Lane i: float4 @ elem 4*i (covers [0,256)), float4 @ 256+4*i for lanes<56
// (covers [256,480)). Segment boundaries 128/320/480 are float4-aligned;
// row stride 1920 B = 30 full cache lines, so stores never split lines.
// Variance via sum(x^2) - n*mean^2 -> single read pass, data held in regs.
// R4 evidence: kernel <239us (absent from rocprof top-5; fills at 240us
// dominate), dur_us=618 includes ~410us harness reset traffic. This round:
// nontemporal loads/stores (stream-once data, keep L2/L3 clean) + uncapped
// one-shot grid (no grid-stride loop, max TLP). Arithmetic unchanged.

#define DIM 480
typedef float f4 __attribute__((ext_vector_type(4)));

__global__ __launch_bounds__(256) void
eln_kernel(const float* __restrict__ feat,
           const float* __restrict__ scale,
           const float* __restrict__ offset0,
           float* __restrict__ out,
           int nrows)
{
    const int wave = threadIdx.x >> 6;          // 0..3, one row per wave
    const int lane = threadIdx.x & 63;
    const long row = (long)blockIdx.x * 4 + wave;
    if (row >= nrows) return;

    const f4* __restrict__ fin =
        reinterpret_cast<const f4*>(feat + row * (long)DIM);
    f4* __restrict__ fout =
        reinterpret_cast<f4*>(out + row * (long)DIM);

    // ---- load (coalesced, 16 B/lane, nontemporal: zero reuse) ----
    f4 a = __builtin_nontemporal_load(fin + lane);   // elems [4*lane,4*lane+4)
    f4 b = {0.f, 0.f, 0.f, 0.f};
    const bool b_ok = (lane < 56);                   // elems [256,480)
    if (b_ok) b = __builtin_nontemporal_load(fin + 64 + lane);

    // ---- per-lane partial sums ----
    // a: lanes 0-31 -> seg0 (scalars), lanes 32-63 -> seg1 (1o, first half)
    // b: lanes 0-15 -> seg1 (1o, rest), lanes 16-55 -> seg2 (2e)
    float s0 = 0.f, q0 = 0.f, q1 = 0.f, q2 = 0.f;
    const float qa = a.x*a.x + a.y*a.y + a.z*a.z + a.w*a.w;
    if (lane < 32) {
        s0 = a.x + a.y + a.z + a.w;
        q0 = qa;
    } else {
        q1 = qa;
    }
    if (b_ok) {
        const float qb = b.x*b.x + b.y*b.y + b.z*b.z + b.w*b.w;
        if (lane < 16) q1 += qb; else q2 += qb;
    }

    // ---- wave (64-lane) butterfly reductions ----
    #pragma unroll
    for (int off = 32; off > 0; off >>= 1) {
        s0 += __shfl_xor(s0, off, 64);
        q0 += __shfl_xor(q0, off, 64);
        q1 += __shfl_xor(q1, off, 64);
        q2 += __shfl_xor(q2, off, 64);
    }

    // ---- per-row stats (identical arithmetic order to R4 -> same absmax) ----
    const float mean = s0 * (1.0f / 128.0f);
    const float v0 = (q0 - 128.0f * mean * mean) * (1.0f / 127.0f);
    const float v1 = q1 * (1.0f / 63.0f);
    const float v2 = q2 * (1.0f / 31.0f);
    const float eps = 1e-8f;
    const float r0 = scale[0] / sqrtf(v0 + eps);
    const float r1 = scale[1] / sqrtf(v1 + eps);
    const float r2 = scale[2] / sqrtf(v2 + eps);
    const float off0 = offset0[0];

    // ---- normalize + write (coalesced, nontemporal) ----
    f4 oa;
    if (lane < 32) {
        oa.x = (a.x - mean) * r0 + off0;
        oa.y = (a.y - mean) * r0 + off0;
        oa.z = (a.z - mean) * r0 + off0;
        oa.w = (a.w - mean) * r0 + off0;
    } else {
        oa.x = a.x * r1;
        oa.y = a.y * r1;
        oa.z = a.z * r1;
        oa.w = a.w * r1;
    }
    __builtin_nontemporal_store(oa, fout + lane);

    if (b_ok) {
        const float rr = (lane < 16) ? r1 : r2;
        f4 ob;
        ob.x = b.x * rr;
        ob.y = b.y * rr;
        ob.z = b.z * rr;
        ob.w = b.w * rr;
        __builtin_nontemporal_store(ob, fout + 64 + lane);
    }
}

extern "C" void kernel_launch(void* const* d_in, const int* in_sizes, int n_in,
                              void* d_out, int out_size, void* d_ws, size_t ws_size,
                              hipStream_t stream)
{
    const float* feat    = (const float*)d_in[0];
    const float* scale   = (const float*)d_in[1];
    const float* offset0 = (const float*)d_in[2];
    float* out = (float*)d_out;

    const int nrows = in_sizes[0] / DIM;          // 200000
    const int blocks = (nrows + 3) / 4;           // one-shot: 4 rows per block
    eln_kernel<<<blocks, 256, 0, stream>>>(feat, scale, offset0, out, nrows);
}